// Round 17
// baseline (78.368 us; speedup 1.0000x reference)
//
#include <hip/hip_runtime.h>
#include <hip/hip_fp16.h>

// out = A @ x, A sparse COO (rows, cols, edge_vals), x [N,64] f32.
//
// Pipeline:
//   1. chunk_sort (1024 thr, fused x->fp16 convert prologue): one block per
//      4096-edge chunk, bucket-sorts into its private pairs[] region
//      (full-line writes), emits u16 offset table.
//   2. transpose_table: [ch][b] -> [b][ch] for contiguous descriptor reads.
//   3. sort_reduce_h8: one block per 64-row bucket; parallel pure-copy
//      staging -> LDS hist -> shfl scan -> u16 index sort -> OCT-EDGE reduce:
//      eighth-wave (8 lanes x 16B half8) owns a row-stream; 8 streams/wave x
//      2 rows x 4-unroll = ~64 loads in flight/wave. Rounds 13-16 proved the
//      lever is in-flight gathers per wave via instruction packing
//      (59->45->41.7us for 1->2->4 edges/instr).
//
// Hard-won rules: inner loops accumulate in REGISTERS; never make an LDS
// atomic data-dependent on a global load in a hot loop (round 6 = 550us);
// staging must be wide/parallel (round 8 = 109us); global scatter writes
// must be block-private regions (rounds 3-5: WRITE = E*64B); occupancy via
// bucket-split is a wash (round 11); bytes are not the constraint (round 12).

#define D_FEAT   64
#define RPB      64             // rows per bucket
#define RPB_BITS 6
#define COL_BITS 17             // col < 2^17; row-in-bucket in bits [17,23)
#define COL_MASK ((1u << COL_BITS) - 1)
#define CAP      1152           // LDS pair cap per bucket (mean 800, +12 sigma)
#define NB_MAX   1600           // max buckets (1563 used)
#define NCH_MAX  400            // max chunks (306 used at 4096)

// ---------------- fallback (round-1 kernel) ----------------
__global__ void spmv_coo_kernel(const float* __restrict__ x,
                                const int* __restrict__ rows,
                                const int* __restrict__ cols,
                                const float* __restrict__ ev,
                                float* __restrict__ out,
                                int n_edges) {
    const int lane = threadIdx.x & 63;
    const int wave_global = blockIdx.x * (blockDim.x >> 6) + (threadIdx.x >> 6);
    const int n_waves = gridDim.x * (blockDim.x >> 6);
    for (int e = wave_global; e < n_edges; e += n_waves) {
        atomicAdd(&out[rows[e] * D_FEAT + lane], ev[e] * x[cols[e] * D_FEAT + lane]);
    }
}

// ------- phase 1: fused convert + per-chunk bucket sort (1024 thr) ---------
__global__ void __launch_bounds__(1024) chunk_sort_kernel(
        const int* __restrict__ rows, const int* __restrict__ cols,
        const float* __restrict__ ev,
        uint2* __restrict__ pairs, unsigned short* __restrict__ table,
        const float4* __restrict__ x4, __half* __restrict__ xh, int n4,
        int n_edges, int nb, int ch_bits) {
    __shared__ int sh_cnt[NB_MAX];
    __shared__ int sh_off[NB_MAX];
    __shared__ int sb[1024];
    const int t = threadIdx.x;
    const int ch = blockIdx.x;
    const int base = ch << ch_bits;
    const int cnt = min(1 << ch_bits, n_edges - base);

    // fused x f32 -> fp16 convert (grid-stride; hides in sort's stalls)
    if (xh) {
        int gid = ch * 1024 + t;
        int stride = gridDim.x * 1024;
        for (int i = gid; i < n4; i += stride) {
            float4 v = x4[i];
            __half2 h0 = __floats2half2_rn(v.x, v.y);
            __half2 h1 = __floats2half2_rn(v.z, v.w);
            ((__half2*)xh)[2 * i]     = h0;
            ((__half2*)xh)[2 * i + 1] = h1;
        }
    }

    for (int i = t; i < nb; i += 1024) sh_cnt[i] = 0;
    __syncthreads();
    for (int i = t; i < cnt; i += 1024)
        atomicAdd(&sh_cnt[rows[base + i] >> RPB_BITS], 1);
    __syncthreads();

    // hierarchical exclusive scan over nb bins
    const int items = (nb + 1023) / 1024;
    const int i0 = t * items;
    int s = 0;
    for (int j = 0; j < items; ++j) {
        int idx = i0 + j;
        if (idx < nb) s += sh_cnt[idx];
    }
    sb[t] = s;
    __syncthreads();
    for (int off = 1; off < 1024; off <<= 1) {
        int tmp = (t >= off) ? sb[t - off] : 0;
        __syncthreads();
        sb[t] += tmp;
        __syncthreads();
    }
    int run = sb[t] - s;
    for (int j = 0; j < items; ++j) {
        int idx = i0 + j;
        if (idx < nb) { sh_off[idx] = run; run += sh_cnt[idx]; }
    }
    __syncthreads();

    unsigned short* trow = table + (size_t)ch * (nb + 1);
    for (int i = t; i < nb; i += 1024) trow[i] = (unsigned short)sh_off[i];
    if (t == 0) trow[nb] = (unsigned short)cnt;
    __syncthreads();

    for (int i = t; i < cnt; i += 1024) {
        int r = rows[base + i];
        int bk = r >> RPB_BITS;
        int pos = atomicAdd(&sh_off[bk], 1);
        uint2 p;
        p.x = (unsigned)cols[base + i] | ((unsigned)(r & (RPB - 1)) << COL_BITS);
        p.y = __float_as_uint(ev[base + i]);
        pairs[base + pos] = p;
    }
}

// ------------- phase 2: table transpose [ch][b] -> [b][ch] -----------------
#define TT 64
__global__ void __launch_bounds__(256) transpose_table_kernel(
        const unsigned short* __restrict__ table,
        unsigned short* __restrict__ tableT,
        int nch, int ncols /* nb+1 */) {
    __shared__ unsigned short tile[TT][TT + 1];
    const int r0 = blockIdx.x * TT;
    const int c0 = blockIdx.y * TT;
    for (int idx = threadIdx.x; idx < TT * TT; idx += 256) {
        int r = idx >> 6, c = idx & 63;
        int ch = r0 + r, b = c0 + c;
        tile[r][c] = (ch < nch && b < ncols) ? table[(size_t)ch * ncols + b] : 0;
    }
    __syncthreads();
    for (int idx = threadIdx.x; idx < TT * TT; idx += 256) {
        int b = idx >> 6, c = idx & 63;
        int gb = c0 + b, gch = r0 + c;
        if (gb < ncols && gch < nch)
            tableT[(size_t)gb * nch + gch] = tile[c][b];
    }
}

// ------------- phase 3a: f32 fallback reduce (round-12 structure) ----------
__global__ void __launch_bounds__(256) sort_reduce_f32_kernel(
        const float* __restrict__ x,
        const uint2* __restrict__ pairs,
        const unsigned short* __restrict__ table,
        const unsigned short* __restrict__ tableT,
        float* __restrict__ out,
        int n_rows, int nb, int nch, int ch_bits, int use_tt) {
    __shared__ uint2 buf[CAP];
    __shared__ unsigned short srt16[CAP];
    __shared__ unsigned short scnt16[NCH_MAX];
    __shared__ unsigned short soff16[NCH_MAX];
    __shared__ unsigned short sst16[NCH_MAX];
    __shared__ int sb[256];
    __shared__ int hist[RPB + 1];
    __shared__ int lcur[RPB];
    const int t = threadIdx.x;
    const int lane = t & 63;
    const int w = t >> 6;
    const int b = blockIdx.x;

    const int items = (nch + 255) / 256;
    const int c0 = t * items;
    int s = 0;
    if (use_tt) {
        const unsigned short* rowB0 = tableT + (size_t)b * nch;
        const unsigned short* rowB1 = tableT + (size_t)(b + 1) * nch;
        for (int j = 0; j < items; ++j) {
            int ch = c0 + j;
            if (ch < nch) {
                int o1 = rowB0[ch], o2 = rowB1[ch];
                scnt16[ch] = (unsigned short)(o2 - o1);
                soff16[ch] = (unsigned short)o1;
                s += o2 - o1;
            }
        }
    } else {
        for (int j = 0; j < items; ++j) {
            int ch = c0 + j;
            if (ch < nch) {
                const unsigned short* trow = table + (size_t)ch * (nb + 1) + b;
                int o1 = trow[0], o2 = trow[1];
                scnt16[ch] = (unsigned short)(o2 - o1);
                soff16[ch] = (unsigned short)o1;
                s += o2 - o1;
            }
        }
    }
    sb[t] = s;
    __syncthreads();
    for (int off = 1; off < 256; off <<= 1) {
        int tmp = (t >= off) ? sb[t - off] : 0;
        __syncthreads();
        sb[t] += tmp;
        __syncthreads();
    }
    const int total = sb[255];
    int run = sb[t] - s;
    for (int j = 0; j < items; ++j) {
        int ch = c0 + j;
        if (ch < nch) { sst16[ch] = (unsigned short)run; run += scnt16[ch]; }
    }
    if (t <= RPB) hist[t] = 0;
    __syncthreads();

    if (total <= CAP) {
        const int g = t >> 2;
        const int sl = t & 3;
        for (int ch = g; ch < nch; ch += 64) {
            const int c = scnt16[ch];
            const int cbase = (ch << ch_bits) + soff16[ch];
            const int dst = sst16[ch];
            for (int k = sl; k < c; k += 4)
                buf[dst + k] = pairs[cbase + k];
        }
        __syncthreads();
        const unsigned* bufx = (const unsigned*)buf;
        for (int i = t; i < total; i += 256)
            atomicAdd(&hist[1 + (int)(bufx[2 * i] >> COL_BITS)], 1);
        __syncthreads();
        if (w == 0) {
            int v = hist[1 + lane];
            for (int d = 1; d < 64; d <<= 1) {
                int n = __shfl_up(v, d);
                if (lane >= d) v += n;
            }
            hist[1 + lane] = v;
        }
        __syncthreads();
        if (w == 0) lcur[lane] = hist[lane];
        __syncthreads();
        for (int i = t; i < total; i += 256) {
            int rl = (int)(bufx[2 * i] >> COL_BITS);
            int pos = atomicAdd(&lcur[rl], 1);
            srt16[pos] = (unsigned short)i;
        }
        __syncthreads();
        const float* xl = x + lane;
        for (int q = 0; q < RPB / 8; ++q) {
            const int rA = w + 8 * q;
            const int rB = rA + 4;
            int jA = hist[rA], eA = hist[rA + 1];
            int jB = hist[rB], eB = hist[rB + 1];
            float aA0 = 0.f, aA1 = 0.f, aB0 = 0.f, aB1 = 0.f;
            #define GF(P) (__uint_as_float((P).y) * xl[(int)((P).x & COL_MASK) * D_FEAT])
            while (jA + 4 <= eA && jB + 4 <= eB) {
                uint2 pa0 = buf[srt16[jA]], pa1 = buf[srt16[jA + 1]];
                uint2 pa2 = buf[srt16[jA + 2]], pa3 = buf[srt16[jA + 3]];
                uint2 pb0 = buf[srt16[jB]], pb1 = buf[srt16[jB + 1]];
                uint2 pb2 = buf[srt16[jB + 2]], pb3 = buf[srt16[jB + 3]];
                aA0 += GF(pa0); aA1 += GF(pa1); aA0 += GF(pa2); aA1 += GF(pa3);
                aB0 += GF(pb0); aB1 += GF(pb1); aB0 += GF(pb2); aB1 += GF(pb3);
                jA += 4; jB += 4;
            }
            while (jA + 2 <= eA) {
                uint2 p0 = buf[srt16[jA]], p1 = buf[srt16[jA + 1]];
                aA0 += GF(p0); aA1 += GF(p1); jA += 2;
            }
            while (jB + 2 <= eB) {
                uint2 p0 = buf[srt16[jB]], p1 = buf[srt16[jB + 1]];
                aB0 += GF(p0); aB1 += GF(p1); jB += 2;
            }
            if (jA < eA) { uint2 p0 = buf[srt16[jA]]; aA0 += GF(p0); }
            if (jB < eB) { uint2 p0 = buf[srt16[jB]]; aB0 += GF(p0); }
            #undef GF
            const int rowA = b * RPB + rA;
            const int rowB = b * RPB + rB;
            if (rowA < n_rows) out[rowA * D_FEAT + lane] = aA0 + aA1;
            if (rowB < n_rows) out[rowB * D_FEAT + lane] = aB0 + aB1;
        }
    } else {
        for (int r = w; r < RPB; r += 4) {
            const int row = b * RPB + r;
            if (row < n_rows) out[row * D_FEAT + lane] = 0.0f;
        }
        __syncthreads();
        for (int ch = w; ch < nch; ch += 4) {
            const int cbase = (ch << ch_bits) + soff16[ch];
            const int c = scnt16[ch];
            for (int k = 0; k < c; ++k) {
                const uint2 p = pairs[cbase + k];
                const int rl = (int)(p.x >> COL_BITS);
                const int cc = (int)(p.x & COL_MASK);
                const float m = __uint_as_float(p.y) * x[cc * D_FEAT + lane];
                const int row = b * RPB + rl;
                if (row < n_rows) atomicAdd(&out[row * D_FEAT + lane], m);
            }
        }
    }
}

// ------------- phase 3b: fp16 half8 OCT-EDGE reduce ------------------------
// Eighth-wave e (8 lanes) owns row-stream S = w*8+e, rows {S, S+32}; each
// lane covers features {8*ql..8*ql+7} via one 16B load (x-row = 128B =
// 8 lanes x 16B). 8 edges per VMEM instruction; ~64 loads in flight/wave.
__global__ void __launch_bounds__(256) sort_reduce_h8_kernel(
        const __half* __restrict__ x,
        const uint2* __restrict__ pairs,
        const unsigned short* __restrict__ table,
        const unsigned short* __restrict__ tableT,
        float* __restrict__ out,
        int n_rows, int nb, int nch, int ch_bits, int use_tt) {
    __shared__ uint2 buf[CAP];
    __shared__ unsigned short srt16[CAP];
    __shared__ unsigned short scnt16[NCH_MAX];
    __shared__ unsigned short soff16[NCH_MAX];
    __shared__ unsigned short sst16[NCH_MAX];
    __shared__ int sb[256];
    __shared__ int hist[RPB + 1];
    __shared__ int lcur[RPB];
    const int t = threadIdx.x;
    const int lane = t & 63;
    const int w = t >> 6;
    const int b = blockIdx.x;

    const int items = (nch + 255) / 256;
    const int c0 = t * items;
    int s = 0;
    if (use_tt) {
        const unsigned short* rowB0 = tableT + (size_t)b * nch;
        const unsigned short* rowB1 = tableT + (size_t)(b + 1) * nch;
        for (int j = 0; j < items; ++j) {
            int ch = c0 + j;
            if (ch < nch) {
                int o1 = rowB0[ch], o2 = rowB1[ch];
                scnt16[ch] = (unsigned short)(o2 - o1);
                soff16[ch] = (unsigned short)o1;
                s += o2 - o1;
            }
        }
    } else {
        for (int j = 0; j < items; ++j) {
            int ch = c0 + j;
            if (ch < nch) {
                const unsigned short* trow = table + (size_t)ch * (nb + 1) + b;
                int o1 = trow[0], o2 = trow[1];
                scnt16[ch] = (unsigned short)(o2 - o1);
                soff16[ch] = (unsigned short)o1;
                s += o2 - o1;
            }
        }
    }
    sb[t] = s;
    __syncthreads();
    for (int off = 1; off < 256; off <<= 1) {
        int tmp = (t >= off) ? sb[t - off] : 0;
        __syncthreads();
        sb[t] += tmp;
        __syncthreads();
    }
    const int total = sb[255];
    int run = sb[t] - s;
    for (int j = 0; j < items; ++j) {
        int ch = c0 + j;
        if (ch < nch) { sst16[ch] = (unsigned short)run; run += scnt16[ch]; }
    }
    if (t <= RPB) hist[t] = 0;
    __syncthreads();

    if (total <= CAP) {
        const int g = t >> 2;
        const int sl = t & 3;
        for (int ch = g; ch < nch; ch += 64) {
            const int c = scnt16[ch];
            const int cbase = (ch << ch_bits) + soff16[ch];
            const int dst = sst16[ch];
            for (int k = sl; k < c; k += 4)
                buf[dst + k] = pairs[cbase + k];
        }
        __syncthreads();
        const unsigned* bufx = (const unsigned*)buf;
        for (int i = t; i < total; i += 256)
            atomicAdd(&hist[1 + (int)(bufx[2 * i] >> COL_BITS)], 1);
        __syncthreads();
        if (w == 0) {
            int v = hist[1 + lane];
            for (int d = 1; d < 64; d <<= 1) {
                int n = __shfl_up(v, d);
                if (lane >= d) v += n;
            }
            hist[1 + lane] = v;
        }
        __syncthreads();
        if (w == 0) lcur[lane] = hist[lane];
        __syncthreads();
        for (int i = t; i < total; i += 256) {
            int rl = (int)(bufx[2 * i] >> COL_BITS);
            int pos = atomicAdd(&lcur[rl], 1);
            srt16[pos] = (unsigned short)i;
        }
        __syncthreads();

        // oct-edge reduce: stream S = w*8 + (lane>>3); rows {S, S+32};
        // lane covers 8 features via one float4-of-halves load per edge.
        const int S = w * 8 + (lane >> 3);      // 0..31
        const int ql = lane & 7;
        const __half* xb = x + 8 * ql;
        #define GH8(P, AL, AH) do { \
            const int _c = (int)((P).x & COL_MASK); \
            const float _e = __uint_as_float((P).y); \
            const float4 _raw = *(const float4*)(xb + _c * D_FEAT); \
            const float2 _f01 = __half22float2(*(const __half2*)&_raw.x); \
            const float2 _f23 = __half22float2(*(const __half2*)&_raw.y); \
            const float2 _f45 = __half22float2(*(const __half2*)&_raw.z); \
            const float2 _f67 = __half22float2(*(const __half2*)&_raw.w); \
            AL.x += _e * _f01.x; AL.y += _e * _f01.y; \
            AL.z += _e * _f23.x; AL.w += _e * _f23.y; \
            AH.x += _e * _f45.x; AH.y += _e * _f45.y; \
            AH.z += _e * _f67.x; AH.w += _e * _f67.y; } while (0)

        const int rA = S;
        const int rB = S + 32;
        int jA = hist[rA], eA = hist[rA + 1];
        int jB = hist[rB], eB = hist[rB + 1];
        float4 aA0l = {0,0,0,0}, aA0h = {0,0,0,0};
        float4 aA1l = {0,0,0,0}, aA1h = {0,0,0,0};
        float4 aB0l = {0,0,0,0}, aB0h = {0,0,0,0};
        float4 aB1l = {0,0,0,0}, aB1h = {0,0,0,0};
        while (jA + 4 <= eA && jB + 4 <= eB) {
            uint2 qa0 = buf[srt16[jA]], qa1 = buf[srt16[jA + 1]];
            uint2 qa2 = buf[srt16[jA + 2]], qa3 = buf[srt16[jA + 3]];
            uint2 qb0 = buf[srt16[jB]], qb1 = buf[srt16[jB + 1]];
            uint2 qb2 = buf[srt16[jB + 2]], qb3 = buf[srt16[jB + 3]];
            GH8(qa0, aA0l, aA0h); GH8(qa1, aA1l, aA1h);
            GH8(qa2, aA0l, aA0h); GH8(qa3, aA1l, aA1h);
            GH8(qb0, aB0l, aB0h); GH8(qb1, aB1l, aB1h);
            GH8(qb2, aB0l, aB0h); GH8(qb3, aB1l, aB1h);
            jA += 4; jB += 4;
        }
        while (jA + 2 <= eA) {
            uint2 q0 = buf[srt16[jA]], q1 = buf[srt16[jA + 1]];
            GH8(q0, aA0l, aA0h); GH8(q1, aA1l, aA1h); jA += 2;
        }
        while (jB + 2 <= eB) {
            uint2 q0 = buf[srt16[jB]], q1 = buf[srt16[jB + 1]];
            GH8(q0, aB0l, aB0h); GH8(q1, aB1l, aB1h); jB += 2;
        }
        if (jA < eA) { uint2 q0 = buf[srt16[jA]]; GH8(q0, aA0l, aA0h); }
        if (jB < eB) { uint2 q0 = buf[srt16[jB]]; GH8(q0, aB0l, aB0h); }
        #undef GH8

        const int rowA = b * RPB + rA;
        const int rowB = b * RPB + rB;
        if (rowA < n_rows) {
            float4 lo, hi;
            lo.x = aA0l.x + aA1l.x; lo.y = aA0l.y + aA1l.y;
            lo.z = aA0l.z + aA1l.z; lo.w = aA0l.w + aA1l.w;
            hi.x = aA0h.x + aA1h.x; hi.y = aA0h.y + aA1h.y;
            hi.z = aA0h.z + aA1h.z; hi.w = aA0h.w + aA1h.w;
            *(float4*)(out + rowA * D_FEAT + 8 * ql)     = lo;
            *(float4*)(out + rowA * D_FEAT + 8 * ql + 4) = hi;
        }
        if (rowB < n_rows) {
            float4 lo, hi;
            lo.x = aB0l.x + aB1l.x; lo.y = aB0l.y + aB1l.y;
            lo.z = aB0l.z + aB1l.z; lo.w = aB0l.w + aB1l.w;
            hi.x = aB0h.x + aB1h.x; hi.y = aB0h.y + aB1h.y;
            hi.z = aB0h.z + aB1h.z; hi.w = aB0h.w + aB1h.w;
            *(float4*)(out + rowB * D_FEAT + 8 * ql)     = lo;
            *(float4*)(out + rowB * D_FEAT + 8 * ql + 4) = hi;
        }
    } else {
        for (int r = w; r < RPB; r += 4) {
            const int row = b * RPB + r;
            if (row < n_rows) out[row * D_FEAT + lane] = 0.0f;
        }
        __syncthreads();
        for (int ch = w; ch < nch; ch += 4) {
            const int cbase = (ch << ch_bits) + soff16[ch];
            const int c = scnt16[ch];
            for (int k = 0; k < c; ++k) {
                const uint2 p = pairs[cbase + k];
                const int rl = (int)(p.x >> COL_BITS);
                const int cc = (int)(p.x & COL_MASK);
                const float m = __uint_as_float(p.y) *
                                __half2float(x[cc * D_FEAT + lane]);
                const int row = b * RPB + rl;
                if (row < n_rows) atomicAdd(&out[row * D_FEAT + lane], m);
            }
        }
    }
}

extern "C" void kernel_launch(void* const* d_in, const int* in_sizes, int n_in,
                              void* d_out, int out_size, void* d_ws, size_t ws_size,
                              hipStream_t stream) {
    const float* x    = (const float*)d_in[1];
    const int*   rows = (const int*)d_in[2];
    const int*   cols = (const int*)d_in[3];
    const float* ev   = (const float*)d_in[4];
    float* out = (float*)d_out;
    const int n_edges = in_sizes[3];
    const int n_rows  = out_size / D_FEAT;
    const int n_x     = in_sizes[1];
    const int n_cols  = n_x / D_FEAT;
    const int nb = (n_rows + RPB - 1) / RPB;

    int ch_bits = 0, nch = 0, use_tt = 0, use_fp16 = 0;
    size_t off_table = 0, off_tableT = 0, off_xh = 0;
    for (int cb = 12; cb <= 13 && ch_bits == 0; ++cb) {
        int nc = (n_edges + (1 << cb) - 1) >> cb;
        size_t pairs_b = ((size_t)nc << cb) * 8;
        size_t tab_b = (size_t)nc * (size_t)(nb + 1) * 2;
        if (nc <= NCH_MAX && ws_size >= pairs_b + tab_b) {
            ch_bits = cb; nch = nc;
            off_table = pairs_b;
            size_t cur = pairs_b + tab_b;
            if (ws_size >= cur + tab_b) {
                use_tt = 1;
                off_tableT = cur;
                cur += tab_b;
            }
            size_t xh_b = (size_t)n_x * 2;
            cur = (cur + 255) & ~(size_t)255;
            if (ws_size >= cur + xh_b && (n_x & 3) == 0) {
                use_fp16 = 1;
                off_xh = cur;
            }
        }
    }

    if (ch_bits == 0 || nb > NB_MAX || n_cols > (1 << COL_BITS) ||
        n_rows > (1 << COL_BITS)) {
        hipMemsetAsync(d_out, 0, (size_t)out_size * sizeof(float), stream);
        spmv_coo_kernel<<<4096, 256, 0, stream>>>(x, rows, cols, ev, out, n_edges);
        return;
    }

    uint2* pairs = (uint2*)d_ws;
    unsigned short* table  = (unsigned short*)((char*)d_ws + off_table);
    unsigned short* tableT = (unsigned short*)((char*)d_ws + off_tableT);
    __half* xh = use_fp16 ? (__half*)((char*)d_ws + off_xh) : nullptr;

    chunk_sort_kernel<<<nch, 1024, 0, stream>>>(
        rows, cols, ev, pairs, table,
        (const float4*)x, xh, n_x / 4,
        n_edges, nb, ch_bits);
    if (use_tt) {
        dim3 tg((nch + TT - 1) / TT, (nb + 1 + TT - 1) / TT);
        transpose_table_kernel<<<tg, 256, 0, stream>>>(table, tableT, nch, nb + 1);
    }
    if (use_fp16)
        sort_reduce_h8_kernel<<<nb, 256, 0, stream>>>(
            xh, pairs, table, tableT, out, n_rows, nb, nch, ch_bits, use_tt);
    else
        sort_reduce_f32_kernel<<<nb, 256, 0, stream>>>(
            x, pairs, table, tableT, out, n_rows, nb, nch, ch_bits, use_tt);
}

// Round 18
// 72.232 us; speedup vs baseline: 1.0850x; 1.0850x over previous
//
#include <hip/hip_runtime.h>
#include <hip/hip_fp16.h>

// out = A @ x, A sparse COO (rows, cols, edge_vals), x [N,64] f32.
//
// ROUND-16 CONFIGURATION RESTORED (measured best: 72.0us total).
// Round 17's h8 (8 edges/instr) regressed to 48us: 32 streams x 2 rows
// each -> row-degree variance idles eighth-waves in the lockstep drain
// (occupancy 49->28%). Packing optimum is h4: 1x/2x/4x/8x = 59/45/41.7/48.3us.
//
// Pipeline:
//   1. chunk_sort (1024 thr, fused x->fp16 convert prologue): one block per
//      4096-edge chunk, bucket-sorts into its private pairs[] region
//      (full-line writes), emits u16 offset table.
//   2. transpose_table: [ch][b] -> [b][ch] for contiguous descriptor reads.
//   3. sort_reduce_h4: one block per 64-row bucket; parallel pure-copy
//      staging -> LDS hist -> shfl scan -> u16 index sort -> QUAD-EDGE
//      reduce (quarter-wave owns a row-stream; lane covers 4 features via
//      half4; 4 edges per VMEM instruction).
//
// Lever status (all probed): bytes NOT binding (round 12 halved FETCH, dur
// flat); occupancy NOT binding (rounds 10/11); wave-ILP NOT binding (round
// 13); instruction packing optimal at 4x; prep fused (round 16, -7us).
// Hard rules: register accumulation only (round 6); wide parallel staging
// (round 8); block-private scatter regions (rounds 3-5).

#define D_FEAT   64
#define RPB      64             // rows per bucket
#define RPB_BITS 6
#define COL_BITS 17             // col < 2^17; row-in-bucket in bits [17,23)
#define COL_MASK ((1u << COL_BITS) - 1)
#define CAP      1152           // LDS pair cap per bucket (mean 800, +12 sigma)
#define NB_MAX   1600           // max buckets (1563 used)
#define NCH_MAX  400            // max chunks (306 used at 4096)

// ---------------- fallback (round-1 kernel) ----------------
__global__ void spmv_coo_kernel(const float* __restrict__ x,
                                const int* __restrict__ rows,
                                const int* __restrict__ cols,
                                const float* __restrict__ ev,
                                float* __restrict__ out,
                                int n_edges) {
    const int lane = threadIdx.x & 63;
    const int wave_global = blockIdx.x * (blockDim.x >> 6) + (threadIdx.x >> 6);
    const int n_waves = gridDim.x * (blockDim.x >> 6);
    for (int e = wave_global; e < n_edges; e += n_waves) {
        atomicAdd(&out[rows[e] * D_FEAT + lane], ev[e] * x[cols[e] * D_FEAT + lane]);
    }
}

// ------- phase 1: fused convert + per-chunk bucket sort (1024 thr) ---------
__global__ void __launch_bounds__(1024) chunk_sort_kernel(
        const int* __restrict__ rows, const int* __restrict__ cols,
        const float* __restrict__ ev,
        uint2* __restrict__ pairs, unsigned short* __restrict__ table,
        const float4* __restrict__ x4, __half* __restrict__ xh, int n4,
        int n_edges, int nb, int ch_bits) {
    __shared__ int sh_cnt[NB_MAX];
    __shared__ int sh_off[NB_MAX];
    __shared__ int sb[1024];
    const int t = threadIdx.x;
    const int ch = blockIdx.x;
    const int base = ch << ch_bits;
    const int cnt = min(1 << ch_bits, n_edges - base);

    // fused x f32 -> fp16 convert (grid-stride; hides in sort's stalls)
    if (xh) {
        int gid = ch * 1024 + t;
        int stride = gridDim.x * 1024;
        for (int i = gid; i < n4; i += stride) {
            float4 v = x4[i];
            __half2 h0 = __floats2half2_rn(v.x, v.y);
            __half2 h1 = __floats2half2_rn(v.z, v.w);
            ((__half2*)xh)[2 * i]     = h0;
            ((__half2*)xh)[2 * i + 1] = h1;
        }
    }

    for (int i = t; i < nb; i += 1024) sh_cnt[i] = 0;
    __syncthreads();
    for (int i = t; i < cnt; i += 1024)
        atomicAdd(&sh_cnt[rows[base + i] >> RPB_BITS], 1);
    __syncthreads();

    // hierarchical exclusive scan over nb bins
    const int items = (nb + 1023) / 1024;
    const int i0 = t * items;
    int s = 0;
    for (int j = 0; j < items; ++j) {
        int idx = i0 + j;
        if (idx < nb) s += sh_cnt[idx];
    }
    sb[t] = s;
    __syncthreads();
    for (int off = 1; off < 1024; off <<= 1) {
        int tmp = (t >= off) ? sb[t - off] : 0;
        __syncthreads();
        sb[t] += tmp;
        __syncthreads();
    }
    int run = sb[t] - s;
    for (int j = 0; j < items; ++j) {
        int idx = i0 + j;
        if (idx < nb) { sh_off[idx] = run; run += sh_cnt[idx]; }
    }
    __syncthreads();

    unsigned short* trow = table + (size_t)ch * (nb + 1);
    for (int i = t; i < nb; i += 1024) trow[i] = (unsigned short)sh_off[i];
    if (t == 0) trow[nb] = (unsigned short)cnt;
    __syncthreads();

    for (int i = t; i < cnt; i += 1024) {
        int r = rows[base + i];
        int bk = r >> RPB_BITS;
        int pos = atomicAdd(&sh_off[bk], 1);
        uint2 p;
        p.x = (unsigned)cols[base + i] | ((unsigned)(r & (RPB - 1)) << COL_BITS);
        p.y = __float_as_uint(ev[base + i]);
        pairs[base + pos] = p;
    }
}

// ------------- phase 2: table transpose [ch][b] -> [b][ch] -----------------
#define TT 64
__global__ void __launch_bounds__(256) transpose_table_kernel(
        const unsigned short* __restrict__ table,
        unsigned short* __restrict__ tableT,
        int nch, int ncols /* nb+1 */) {
    __shared__ unsigned short tile[TT][TT + 1];
    const int r0 = blockIdx.x * TT;
    const int c0 = blockIdx.y * TT;
    for (int idx = threadIdx.x; idx < TT * TT; idx += 256) {
        int r = idx >> 6, c = idx & 63;
        int ch = r0 + r, b = c0 + c;
        tile[r][c] = (ch < nch && b < ncols) ? table[(size_t)ch * ncols + b] : 0;
    }
    __syncthreads();
    for (int idx = threadIdx.x; idx < TT * TT; idx += 256) {
        int b = idx >> 6, c = idx & 63;
        int gb = c0 + b, gch = r0 + c;
        if (gb < ncols && gch < nch)
            tableT[(size_t)gb * nch + gch] = tile[c][b];
    }
}

// ------------- phase 3a: f32 fallback reduce (round-12 structure) ----------
__global__ void __launch_bounds__(256) sort_reduce_f32_kernel(
        const float* __restrict__ x,
        const uint2* __restrict__ pairs,
        const unsigned short* __restrict__ table,
        const unsigned short* __restrict__ tableT,
        float* __restrict__ out,
        int n_rows, int nb, int nch, int ch_bits, int use_tt) {
    __shared__ uint2 buf[CAP];
    __shared__ unsigned short srt16[CAP];
    __shared__ unsigned short scnt16[NCH_MAX];
    __shared__ unsigned short soff16[NCH_MAX];
    __shared__ unsigned short sst16[NCH_MAX];
    __shared__ int sb[256];
    __shared__ int hist[RPB + 1];
    __shared__ int lcur[RPB];
    const int t = threadIdx.x;
    const int lane = t & 63;
    const int w = t >> 6;
    const int b = blockIdx.x;

    const int items = (nch + 255) / 256;
    const int c0 = t * items;
    int s = 0;
    if (use_tt) {
        const unsigned short* rowB0 = tableT + (size_t)b * nch;
        const unsigned short* rowB1 = tableT + (size_t)(b + 1) * nch;
        for (int j = 0; j < items; ++j) {
            int ch = c0 + j;
            if (ch < nch) {
                int o1 = rowB0[ch], o2 = rowB1[ch];
                scnt16[ch] = (unsigned short)(o2 - o1);
                soff16[ch] = (unsigned short)o1;
                s += o2 - o1;
            }
        }
    } else {
        for (int j = 0; j < items; ++j) {
            int ch = c0 + j;
            if (ch < nch) {
                const unsigned short* trow = table + (size_t)ch * (nb + 1) + b;
                int o1 = trow[0], o2 = trow[1];
                scnt16[ch] = (unsigned short)(o2 - o1);
                soff16[ch] = (unsigned short)o1;
                s += o2 - o1;
            }
        }
    }
    sb[t] = s;
    __syncthreads();
    for (int off = 1; off < 256; off <<= 1) {
        int tmp = (t >= off) ? sb[t - off] : 0;
        __syncthreads();
        sb[t] += tmp;
        __syncthreads();
    }
    const int total = sb[255];
    int run = sb[t] - s;
    for (int j = 0; j < items; ++j) {
        int ch = c0 + j;
        if (ch < nch) { sst16[ch] = (unsigned short)run; run += scnt16[ch]; }
    }
    if (t <= RPB) hist[t] = 0;
    __syncthreads();

    if (total <= CAP) {
        const int g = t >> 2;
        const int sl = t & 3;
        for (int ch = g; ch < nch; ch += 64) {
            const int c = scnt16[ch];
            const int cbase = (ch << ch_bits) + soff16[ch];
            const int dst = sst16[ch];
            for (int k = sl; k < c; k += 4)
                buf[dst + k] = pairs[cbase + k];
        }
        __syncthreads();
        const unsigned* bufx = (const unsigned*)buf;
        for (int i = t; i < total; i += 256)
            atomicAdd(&hist[1 + (int)(bufx[2 * i] >> COL_BITS)], 1);
        __syncthreads();
        if (w == 0) {
            int v = hist[1 + lane];
            for (int d = 1; d < 64; d <<= 1) {
                int n = __shfl_up(v, d);
                if (lane >= d) v += n;
            }
            hist[1 + lane] = v;
        }
        __syncthreads();
        if (w == 0) lcur[lane] = hist[lane];
        __syncthreads();
        for (int i = t; i < total; i += 256) {
            int rl = (int)(bufx[2 * i] >> COL_BITS);
            int pos = atomicAdd(&lcur[rl], 1);
            srt16[pos] = (unsigned short)i;
        }
        __syncthreads();
        const float* xl = x + lane;
        for (int q = 0; q < RPB / 8; ++q) {
            const int rA = w + 8 * q;
            const int rB = rA + 4;
            int jA = hist[rA], eA = hist[rA + 1];
            int jB = hist[rB], eB = hist[rB + 1];
            float aA0 = 0.f, aA1 = 0.f, aB0 = 0.f, aB1 = 0.f;
            #define GF(P) (__uint_as_float((P).y) * xl[(int)((P).x & COL_MASK) * D_FEAT])
            while (jA + 4 <= eA && jB + 4 <= eB) {
                uint2 pa0 = buf[srt16[jA]], pa1 = buf[srt16[jA + 1]];
                uint2 pa2 = buf[srt16[jA + 2]], pa3 = buf[srt16[jA + 3]];
                uint2 pb0 = buf[srt16[jB]], pb1 = buf[srt16[jB + 1]];
                uint2 pb2 = buf[srt16[jB + 2]], pb3 = buf[srt16[jB + 3]];
                aA0 += GF(pa0); aA1 += GF(pa1); aA0 += GF(pa2); aA1 += GF(pa3);
                aB0 += GF(pb0); aB1 += GF(pb1); aB0 += GF(pb2); aB1 += GF(pb3);
                jA += 4; jB += 4;
            }
            while (jA + 2 <= eA) {
                uint2 p0 = buf[srt16[jA]], p1 = buf[srt16[jA + 1]];
                aA0 += GF(p0); aA1 += GF(p1); jA += 2;
            }
            while (jB + 2 <= eB) {
                uint2 p0 = buf[srt16[jB]], p1 = buf[srt16[jB + 1]];
                aB0 += GF(p0); aB1 += GF(p1); jB += 2;
            }
            if (jA < eA) { uint2 p0 = buf[srt16[jA]]; aA0 += GF(p0); }
            if (jB < eB) { uint2 p0 = buf[srt16[jB]]; aB0 += GF(p0); }
            #undef GF
            const int rowA = b * RPB + rA;
            const int rowB = b * RPB + rB;
            if (rowA < n_rows) out[rowA * D_FEAT + lane] = aA0 + aA1;
            if (rowB < n_rows) out[rowB * D_FEAT + lane] = aB0 + aB1;
        }
    } else {
        for (int r = w; r < RPB; r += 4) {
            const int row = b * RPB + r;
            if (row < n_rows) out[row * D_FEAT + lane] = 0.0f;
        }
        __syncthreads();
        for (int ch = w; ch < nch; ch += 4) {
            const int cbase = (ch << ch_bits) + soff16[ch];
            const int c = scnt16[ch];
            for (int k = 0; k < c; ++k) {
                const uint2 p = pairs[cbase + k];
                const int rl = (int)(p.x >> COL_BITS);
                const int cc = (int)(p.x & COL_MASK);
                const float m = __uint_as_float(p.y) * x[cc * D_FEAT + lane];
                const int row = b * RPB + rl;
                if (row < n_rows) atomicAdd(&out[row * D_FEAT + lane], m);
            }
        }
    }
}

// ------------- phase 3b: fp16 half4 QUAD-EDGE reduce (round-15/16) ---------
__global__ void __launch_bounds__(256) sort_reduce_h4_kernel(
        const __half* __restrict__ x,
        const uint2* __restrict__ pairs,
        const unsigned short* __restrict__ table,
        const unsigned short* __restrict__ tableT,
        float* __restrict__ out,
        int n_rows, int nb, int nch, int ch_bits, int use_tt) {
    __shared__ uint2 buf[CAP];
    __shared__ unsigned short srt16[CAP];
    __shared__ unsigned short scnt16[NCH_MAX];
    __shared__ unsigned short soff16[NCH_MAX];
    __shared__ unsigned short sst16[NCH_MAX];
    __shared__ int sb[256];
    __shared__ int hist[RPB + 1];
    __shared__ int lcur[RPB];
    const int t = threadIdx.x;
    const int lane = t & 63;
    const int w = t >> 6;
    const int b = blockIdx.x;

    const int items = (nch + 255) / 256;
    const int c0 = t * items;
    int s = 0;
    if (use_tt) {
        const unsigned short* rowB0 = tableT + (size_t)b * nch;
        const unsigned short* rowB1 = tableT + (size_t)(b + 1) * nch;
        for (int j = 0; j < items; ++j) {
            int ch = c0 + j;
            if (ch < nch) {
                int o1 = rowB0[ch], o2 = rowB1[ch];
                scnt16[ch] = (unsigned short)(o2 - o1);
                soff16[ch] = (unsigned short)o1;
                s += o2 - o1;
            }
        }
    } else {
        for (int j = 0; j < items; ++j) {
            int ch = c0 + j;
            if (ch < nch) {
                const unsigned short* trow = table + (size_t)ch * (nb + 1) + b;
                int o1 = trow[0], o2 = trow[1];
                scnt16[ch] = (unsigned short)(o2 - o1);
                soff16[ch] = (unsigned short)o1;
                s += o2 - o1;
            }
        }
    }
    sb[t] = s;
    __syncthreads();
    for (int off = 1; off < 256; off <<= 1) {
        int tmp = (t >= off) ? sb[t - off] : 0;
        __syncthreads();
        sb[t] += tmp;
        __syncthreads();
    }
    const int total = sb[255];
    int run = sb[t] - s;
    for (int j = 0; j < items; ++j) {
        int ch = c0 + j;
        if (ch < nch) { sst16[ch] = (unsigned short)run; run += scnt16[ch]; }
    }
    if (t <= RPB) hist[t] = 0;
    __syncthreads();

    if (total <= CAP) {
        const int g = t >> 2;
        const int sl = t & 3;
        for (int ch = g; ch < nch; ch += 64) {
            const int c = scnt16[ch];
            const int cbase = (ch << ch_bits) + soff16[ch];
            const int dst = sst16[ch];
            for (int k = sl; k < c; k += 4)
                buf[dst + k] = pairs[cbase + k];
        }
        __syncthreads();
        const unsigned* bufx = (const unsigned*)buf;
        for (int i = t; i < total; i += 256)
            atomicAdd(&hist[1 + (int)(bufx[2 * i] >> COL_BITS)], 1);
        __syncthreads();
        if (w == 0) {
            int v = hist[1 + lane];
            for (int d = 1; d < 64; d <<= 1) {
                int n = __shfl_up(v, d);
                if (lane >= d) v += n;
            }
            hist[1 + lane] = v;
        }
        __syncthreads();
        if (w == 0) lcur[lane] = hist[lane];
        __syncthreads();
        for (int i = t; i < total; i += 256) {
            int rl = (int)(bufx[2 * i] >> COL_BITS);
            int pos = atomicAdd(&lcur[rl], 1);
            srt16[pos] = (unsigned short)i;
        }
        __syncthreads();

        // quad-edge reduce: stream S = w*4 + (lane>>4); lane covers 4 features
        const int S = w * 4 + (lane >> 4);      // 0..15
        const int ql = lane & 15;
        const __half* xb = x + 4 * ql;
        #define GH4(P, A) do { \
            const int _c = (int)((P).x & COL_MASK); \
            const float _e = __uint_as_float((P).y); \
            const float2 _raw = *(const float2*)(xb + _c * D_FEAT); \
            const float2 _f01 = __half22float2(*(const __half2*)&_raw.x); \
            const float2 _f23 = __half22float2(*(const __half2*)&_raw.y); \
            A.x += _e * _f01.x; A.y += _e * _f01.y; \
            A.z += _e * _f23.x; A.w += _e * _f23.y; } while (0)
        for (int m = 0; m < 4; m += 2) {
            const int rA = S + 16 * m;
            const int rB = rA + 16;
            int jA = hist[rA], eA = hist[rA + 1];
            int jB = hist[rB], eB = hist[rB + 1];
            float4 aA0 = {0.f, 0.f, 0.f, 0.f}, aA1 = {0.f, 0.f, 0.f, 0.f};
            float4 aB0 = {0.f, 0.f, 0.f, 0.f}, aB1 = {0.f, 0.f, 0.f, 0.f};
            while (jA + 4 <= eA && jB + 4 <= eB) {
                uint2 qa0 = buf[srt16[jA]], qa1 = buf[srt16[jA + 1]];
                uint2 qa2 = buf[srt16[jA + 2]], qa3 = buf[srt16[jA + 3]];
                uint2 qb0 = buf[srt16[jB]], qb1 = buf[srt16[jB + 1]];
                uint2 qb2 = buf[srt16[jB + 2]], qb3 = buf[srt16[jB + 3]];
                GH4(qa0, aA0); GH4(qa1, aA1); GH4(qa2, aA0); GH4(qa3, aA1);
                GH4(qb0, aB0); GH4(qb1, aB1); GH4(qb2, aB0); GH4(qb3, aB1);
                jA += 4; jB += 4;
            }
            while (jA + 2 <= eA) {
                uint2 q0 = buf[srt16[jA]], q1 = buf[srt16[jA + 1]];
                GH4(q0, aA0); GH4(q1, aA1); jA += 2;
            }
            while (jB + 2 <= eB) {
                uint2 q0 = buf[srt16[jB]], q1 = buf[srt16[jB + 1]];
                GH4(q0, aB0); GH4(q1, aB1); jB += 2;
            }
            if (jA < eA) { uint2 q0 = buf[srt16[jA]]; GH4(q0, aA0); }
            if (jB < eB) { uint2 q0 = buf[srt16[jB]]; GH4(q0, aB0); }
            const int rowA = b * RPB + rA;
            const int rowB = b * RPB + rB;
            if (rowA < n_rows) {
                float4 v;
                v.x = aA0.x + aA1.x; v.y = aA0.y + aA1.y;
                v.z = aA0.z + aA1.z; v.w = aA0.w + aA1.w;
                *(float4*)(out + rowA * D_FEAT + 4 * ql) = v;
            }
            if (rowB < n_rows) {
                float4 v;
                v.x = aB0.x + aB1.x; v.y = aB0.y + aB1.y;
                v.z = aB0.z + aB1.z; v.w = aB0.w + aB1.w;
                *(float4*)(out + rowB * D_FEAT + 4 * ql) = v;
            }
        }
        #undef GH4
    } else {
        for (int r = w; r < RPB; r += 4) {
            const int row = b * RPB + r;
            if (row < n_rows) out[row * D_FEAT + lane] = 0.0f;
        }
        __syncthreads();
        for (int ch = w; ch < nch; ch += 4) {
            const int cbase = (ch << ch_bits) + soff16[ch];
            const int c = scnt16[ch];
            for (int k = 0; k < c; ++k) {
                const uint2 p = pairs[cbase + k];
                const int rl = (int)(p.x >> COL_BITS);
                const int cc = (int)(p.x & COL_MASK);
                const float m = __uint_as_float(p.y) *
                                __half2float(x[cc * D_FEAT + lane]);
                const int row = b * RPB + rl;
                if (row < n_rows) atomicAdd(&out[row * D_FEAT + lane], m);
            }
        }
    }
}

extern "C" void kernel_launch(void* const* d_in, const int* in_sizes, int n_in,
                              void* d_out, int out_size, void* d_ws, size_t ws_size,
                              hipStream_t stream) {
    const float* x    = (const float*)d_in[1];
    const int*   rows = (const int*)d_in[2];
    const int*   cols = (const int*)d_in[3];
    const float* ev   = (const float*)d_in[4];
    float* out = (float*)d_out;
    const int n_edges = in_sizes[3];
    const int n_rows  = out_size / D_FEAT;
    const int n_x     = in_sizes[1];
    const int n_cols  = n_x / D_FEAT;
    const int nb = (n_rows + RPB - 1) / RPB;

    int ch_bits = 0, nch = 0, use_tt = 0, use_fp16 = 0;
    size_t off_table = 0, off_tableT = 0, off_xh = 0;
    for (int cb = 12; cb <= 13 && ch_bits == 0; ++cb) {
        int nc = (n_edges + (1 << cb) - 1) >> cb;
        size_t pairs_b = ((size_t)nc << cb) * 8;
        size_t tab_b = (size_t)nc * (size_t)(nb + 1) * 2;
        if (nc <= NCH_MAX && ws_size >= pairs_b + tab_b) {
            ch_bits = cb; nch = nc;
            off_table = pairs_b;
            size_t cur = pairs_b + tab_b;
            if (ws_size >= cur + tab_b) {
                use_tt = 1;
                off_tableT = cur;
                cur += tab_b;
            }
            size_t xh_b = (size_t)n_x * 2;
            cur = (cur + 255) & ~(size_t)255;
            if (ws_size >= cur + xh_b && (n_x & 3) == 0) {
                use_fp16 = 1;
                off_xh = cur;
            }
        }
    }

    if (ch_bits == 0 || nb > NB_MAX || n_cols > (1 << COL_BITS) ||
        n_rows > (1 << COL_BITS)) {
        hipMemsetAsync(d_out, 0, (size_t)out_size * sizeof(float), stream);
        spmv_coo_kernel<<<4096, 256, 0, stream>>>(x, rows, cols, ev, out, n_edges);
        return;
    }

    uint2* pairs = (uint2*)d_ws;
    unsigned short* table  = (unsigned short*)((char*)d_ws + off_table);
    unsigned short* tableT = (unsigned short*)((char*)d_ws + off_tableT);
    __half* xh = use_fp16 ? (__half*)((char*)d_ws + off_xh) : nullptr;

    chunk_sort_kernel<<<nch, 1024, 0, stream>>>(
        rows, cols, ev, pairs, table,
        (const float4*)x, xh, n_x / 4,
        n_edges, nb, ch_bits);
    if (use_tt) {
        dim3 tg((nch + TT - 1) / TT, (nb + 1 + TT - 1) / TT);
        transpose_table_kernel<<<tg, 256, 0, stream>>>(table, tableT, nch, nb + 1);
    }
    if (use_fp16)
        sort_reduce_h4_kernel<<<nb, 256, 0, stream>>>(
            xh, pairs, table, tableT, out, n_rows, nb, nch, ch_bits, use_tt);
    else
        sort_reduce_f32_kernel<<<nb, 256, 0, stream>>>(
            x, pairs, table, tableT, out, n_rows, nb, nch, ch_bits, use_tt);
}